// Round 6
// baseline (536.314 us; speedup 1.0000x reference)
//
#include <hip/hip_runtime.h>
#include <cstdint>
#include <cstddef>

#define B_ 4
#define V1 262144   // 64^3
#define C1 64
#define V2 32768    // 32^3
#define C2 128

// stats layout (float indices within stats buffer)
#define OFF_S1A 0
#define OFF_S2A 128
#define OFF_CNT1 256
#define OFF_S1B 260
#define OFF_S2B 388
#define OFF_CNT2 516

typedef __bf16 bf16x8 __attribute__((ext_vector_type(8)));
typedef float f32x4 __attribute__((ext_vector_type(4)));

__device__ __forceinline__ float bf2f(unsigned short u) {
    return __builtin_bit_cast(float, (unsigned)u << 16);
}
__device__ __forceinline__ unsigned short f2bf(float f) {
    unsigned u = __builtin_bit_cast(unsigned, f);
    u += 0x7fffu + ((u >> 16) & 1u);     // RTNE
    return (unsigned short)(u >> 16);
}

// ---------------- Kernel 0: weight prep -> bf16, frag-contiguous slabs ----------------
// Slab seq order matches kernel loop: seq = s*27 + (dz*9+dy*3+dx); skip slabs last.
// Within slab: [q 4][n 128][j 8], element k = q*8+j (within 32-ch cslice), n = co.
__global__ __launch_bounds__(256) void k0_wprep(const float* __restrict__ w1,
                                                const float* __restrict__ w2,
                                                const float* __restrict__ wskip,
                                                unsigned short* __restrict__ w1t,
                                                unsigned short* __restrict__ w2t)
{
    int i = blockIdx.x * 256 + threadIdx.x;
    if (i < 54 * 4096) {
        int seq = i >> 12, r = i & 4095;
        int q = r >> 10, n = (r >> 3) & 127, j = r & 7;
        int s = seq / 27, t = seq % 27;
        int ci = s * 32 + q * 8 + j;
        w1t[i] = f2bf(w1[((size_t)t * 64 + ci) * 128 + n]);
    }
    int i2 = i - 54 * 4096;
    if (i2 >= 0 && i2 < 110 * 4096) {
        int seq = i2 >> 12, r = i2 & 4095;
        int q = r >> 10, n = (r >> 3) & 127, j = r & 7;
        float v;
        if (seq < 108) {
            int s = seq / 27, t = seq % 27;
            int ci = s * 32 + q * 8 + j;
            v = w2[((size_t)t * 128 + ci) * 128 + n];
        } else {
            int ci = (seq - 108) * 32 + q * 8 + j;
            v = wskip[(size_t)ci * 128 + n];
        }
        w2t[i2] = f2bf(v);
    }
}

// ---------------- Kernel 1: GN1 stats ----------------
__global__ __launch_bounds__(256) void k1_stats1(const float* __restrict__ x,
                                                 const int* __restrict__ mask,
                                                 float* __restrict__ stats)
{
    __shared__ float ls1[32], ls2[32];
    __shared__ float lcnt;
    int tid = threadIdx.x;
    if (tid < 32) { ls1[tid] = 0.f; ls2[tid] = 0.f; }
    if (tid == 0) lcnt = 0.f;
    __syncthreads();

    int b  = blockIdx.x & 3;
    int bb = blockIdx.x >> 2;
    int c4 = tid & 15;
    int vl = tid >> 4;

    const float* xb = x + ((size_t)b * V1) * C1;
    const int*   mb = mask + (size_t)b * V1;

    float s1a = 0.f, s2a = 0.f, s1b = 0.f, s2b = 0.f, mc = 0.f;
    for (int ch = bb; ch < V1 / 16; ch += 1024) {
        int v = ch * 16 + vl;
        int m = mb[v];
        if (c4 == 0) mc += (float)m;
        if (m) {
            float4 xv = *(const float4*)(xb + (size_t)v * C1 + c4 * 4);
            s1a += xv.x + xv.y;  s2a += xv.x * xv.x + xv.y * xv.y;
            s1b += xv.z + xv.w;  s2b += xv.z * xv.z + xv.w * xv.w;
        }
    }
    atomicAdd(&ls1[2 * c4],     s1a); atomicAdd(&ls2[2 * c4],     s2a);
    atomicAdd(&ls1[2 * c4 + 1], s1b); atomicAdd(&ls2[2 * c4 + 1], s2b);
    if (c4 == 0) atomicAdd(&lcnt, mc);
    __syncthreads();
    if (tid < 32) {
        atomicAdd(&stats[OFF_S1A + b * 32 + tid], ls1[tid]);
        atomicAdd(&stats[OFF_S2A + b * 32 + tid], ls2[tid]);
    }
    if (tid == 0) atomicAdd(&stats[OFF_CNT1 + b], lcnt);
}

// ------ Kernel 2: GN1 apply + SiLU + downsample -> h1b (bf16), xd -> xdb (bf16), dm ------
__global__ __launch_bounds__(256) void k2_down(const float* __restrict__ x,
                                               const int* __restrict__ mask,
                                               const float* __restrict__ gn1w,
                                               const float* __restrict__ gn1b,
                                               const float* __restrict__ stats,
                                               unsigned short* __restrict__ h1b,
                                               unsigned short* __restrict__ xdb,
                                               float* __restrict__ dm)
{
    int tid = threadIdx.x;
    int c  = tid & 63;
    int vl = tid >> 6;
    size_t ov = (size_t)blockIdx.x * 4 + vl;
    int b  = (int)(ov >> 15);
    int v2 = (int)(ov & 32767);
    int z = v2 >> 10, y = (v2 >> 5) & 31, xk = v2 & 31;

    int g = c >> 1;
    float ce   = fmaxf(stats[OFF_CNT1 + b] * 2.f, 1.f);
    float mean = stats[OFF_S1A + b * 32 + g] / ce;
    float var  = stats[OFF_S2A + b * 32 + g] / ce - mean * mean;
    float rinv = rsqrtf(var + 1e-5f);
    float a  = rinv * gn1w[c];
    float bc = gn1b[c] - mean * a;

    const int*   mb = mask + ((size_t)b << 18);
    const float* xb = x + (((size_t)b << 18) << 6);

    float hacc = 0.f, xacc = 0.f; int cnt = 0;
    #pragma unroll
    for (int dz = 0; dz < 2; ++dz)
    #pragma unroll
    for (int dy = 0; dy < 2; ++dy)
    #pragma unroll
    for (int dx = 0; dx < 2; ++dx) {
        int v1 = ((2 * z + dz) << 12) | ((2 * y + dy) << 6) | (2 * xk + dx);
        if (mb[v1]) {
            cnt++;
            float xv = xb[(size_t)v1 * 64 + c];
            xacc += xv;
            float yv = fmaf(xv, a, bc);
            hacc += yv / (1.f + expf(-yv));
        }
    }
    float inv = 1.f / fmaxf((float)cnt, 1.f);
    h1b[ov * 64 + c] = f2bf(hacc * inv);
    xdb[ov * 64 + c] = f2bf(xacc * inv);
    if (c == 0) dm[ov] = (cnt > 0) ? 1.f : 0.f;
}

// ---------------- MFMA implicit-GEMM conv 3x3x3 (+optional 1x1 skip taps) ----------------
// Block tile M=128 (4 y-rows at one (b,z)) x N=128. 4 waves: wm (y-pair) x wn (N-half).
// Wave tile M=64 x N=64: acc[4][4] f32x4 = 64 VGPR.
// A staged in LDS per (s,dz) superstep: [q4][vox 6*34][j8]; in-loop A = ds_read, offset imm.
// B slab (8KB) double-buffered, 2-step-ahead reg prefetch pipeline.
template<int CIN, bool SKIP>
__global__ __launch_bounds__(256, 4) void conv3_mfma(
    const unsigned short* __restrict__ src,
    const unsigned short* __restrict__ sksrc,
    const unsigned short* __restrict__ wT,
    const float* __restrict__ bias,
    const float* __restrict__ bias2,
    const float* __restrict__ dm,
    float* __restrict__ outf,
    unsigned short* __restrict__ outb)
{
    constexpr int CS  = CIN / 32;
    constexpr int NKM = 27 * CS;
    constexpr int NK  = NKM + (SKIP ? 2 : 0);
    constexpr int ACH = 4 * 204;            // A-tile 16B chunks (816)

    __shared__ short aT[4 * 204 * 8];       // 13056 B
    __shared__ short bS[2][4096];           // 16 KB

    const int tid  = threadIdx.x;
    const int lane = tid & 63;
    const int wv   = tid >> 6;
    const int wm   = wv >> 1;               // y-pair within block
    const int wn   = wv & 1;                // N-half
    const int orig = blockIdx.x;
    const int blk  = (orig & 7) * 128 + (orig >> 3);   // bijective XCD swizzle
    const int b    = blk >> 8;
    const int z    = (blk >> 3) & 31;
    const int yo   = blk & 7;
    const int vb   = b * 32768;
    const int xl   = lane & 15;
    const int q    = lane >> 4;
    const int klo  = q * 8;

    const uint4* wT4 = (const uint4*)wT;

    f32x4 acc[4][4];
    #pragma unroll
    for (int f = 0; f < 4; ++f)
        #pragma unroll
        for (int nb = 0; nb < 4; ++nb)
            acc[f][nb] = (f32x4){0.f, 0.f, 0.f, 0.f};

    // A-tile read bases (shorts): chunk (q, vox= (wm*2+fy+dy)*34 + fx*16+xl+dx)
    const short* aR00 = aT + (size_t)(q * 204 + (wm * 2 + 0) * 34 + 0 * 16 + xl) * 8;
    const short* aR01 = aT + (size_t)(q * 204 + (wm * 2 + 0) * 34 + 1 * 16 + xl) * 8;
    const short* aR10 = aT + (size_t)(q * 204 + (wm * 2 + 1) * 34 + 0 * 16 + xl) * 8;
    const short* aR11 = aT + (size_t)(q * 204 + (wm * 2 + 1) * 34 + 1 * 16 + xl) * 8;
    const int bOff = q * 1024 + (wn * 64 + xl) * 8;    // shorts, + nb*128

    // ---- prologue: slab 0 -> LDS buf0, slab 1 -> regs ----
    uint4 qn0 = {0,0,0,0}, qn1 = {0,0,0,0};
    {
        uint4 p0 = wT4[tid], p1 = wT4[tid + 256];
        ((uint4*)&bS[0][0])[tid] = p0;
        ((uint4*)&bS[0][0])[tid + 256] = p1;
        if (NK > 1) { qn0 = wT4[512 + tid]; qn1 = wT4[768 + tid]; }
    }
    // (visibility of bS[0] covered by first staging barrier)

    int ks = 0, cur = 0;
    #pragma clang loop unroll(disable)
    for (int s = 0; s < CS; ++s) {
        #pragma clang loop unroll(disable)
        for (int dz = 0; dz < 3; ++dz) {
            const int zz = z + dz - 1;
            const bool zok = (unsigned)zz < 32u;
            // ---- stage A-tile for (s, zz): issue loads, barrier, write, barrier ----
            uint4 av0 = {0,0,0,0}, av1 = {0,0,0,0}, av2 = {0,0,0,0}, av3 = {0,0,0,0};
            {
                #pragma unroll
                for (int r = 0; r < 4; ++r) {
                    int c = tid + r * 256;
                    uint4 v = {0,0,0,0};
                    if (c < ACH) {
                        int qq  = c / 204, vox = c % 204;
                        int yy  = vox / 34, xx = vox % 34;
                        int y   = yo * 4 + yy - 1, xg = xx - 1;
                        if (zok && (unsigned)y < 32u && (unsigned)xg < 32u)
                            v = *(const uint4*)(src +
                                (size_t)(vb + zz * 1024 + y * 32 + xg) * CIN + s * 32 + qq * 8);
                    }
                    if (r == 0) av0 = v; else if (r == 1) av1 = v;
                    else if (r == 2) av2 = v; else av3 = v;
                }
            }
            __syncthreads();   // prior taps done reading aT / prologue bS visible
            {
                uint4* at4 = (uint4*)aT;
                if (tid < ACH)        at4[tid] = av0;
                at4[tid + 256] = av1;
                at4[tid + 512] = av2;
                if (tid + 768 < ACH)  at4[tid + 768] = av3;
            }
            __syncthreads();   // A-tile ready

            #pragma unroll
            for (int t9 = 0; t9 < 9; ++t9) {
                const int dy = t9 / 3, dx = t9 % 3;     // static after unroll
                // issue slab ks+2 global loads
                uint4 r0 = {0,0,0,0}, r1 = {0,0,0,0};
                if (ks + 2 < NK) {
                    r0 = wT4[(size_t)(ks + 2) * 512 + tid];
                    r1 = wT4[(size_t)(ks + 2) * 512 + 256 + tid];
                }
                // A frags from LDS (offset immediates)
                const int ao = (dy * 34 + dx) * 8;
                bf16x8 a00 = *(const bf16x8*)(aR00 + ao);
                bf16x8 a01 = *(const bf16x8*)(aR01 + ao);
                bf16x8 a10 = *(const bf16x8*)(aR10 + ao);
                bf16x8 a11 = *(const bf16x8*)(aR11 + ao);
                // B frags + MFMA
                const short* bp = &bS[cur][0] + bOff;
                #pragma unroll
                for (int nb = 0; nb < 4; ++nb) {
                    bf16x8 bf = *(const bf16x8*)(bp + nb * 128);
                    acc[0][nb] = __builtin_amdgcn_mfma_f32_16x16x32_bf16(a00, bf, acc[0][nb], 0, 0, 0);
                    acc[1][nb] = __builtin_amdgcn_mfma_f32_16x16x32_bf16(a01, bf, acc[1][nb], 0, 0, 0);
                    acc[2][nb] = __builtin_amdgcn_mfma_f32_16x16x32_bf16(a10, bf, acc[2][nb], 0, 0, 0);
                    acc[3][nb] = __builtin_amdgcn_mfma_f32_16x16x32_bf16(a11, bf, acc[3][nb], 0, 0, 0);
                }
                // write-late: slab ks+1 into other buffer
                if (ks + 1 < NK) {
                    ((uint4*)&bS[cur ^ 1][0])[tid] = qn0;
                    ((uint4*)&bS[cur ^ 1][0])[tid + 256] = qn1;
                }
                __syncthreads();
                qn0 = r0; qn1 = r1;
                cur ^= 1; ++ks;
            }
        }
    }

    if constexpr (SKIP) {
        #pragma unroll
        for (int ss = 0; ss < 2; ++ss) {
            uint4 r0 = {0,0,0,0}, r1 = {0,0,0,0};
            if (ks + 2 < NK) {
                r0 = wT4[(size_t)(ks + 2) * 512 + tid];
                r1 = wT4[(size_t)(ks + 2) * 512 + 256 + tid];
            }
            const size_t rowb = (size_t)(vb + z * 1024 + (yo * 4 + wm * 2) * 32);
            bf16x8 a00 = *(const bf16x8*)(sksrc + (rowb + 0 * 32 + 0 * 16 + xl) * 64 + ss * 32 + klo);
            bf16x8 a01 = *(const bf16x8*)(sksrc + (rowb + 0 * 32 + 1 * 16 + xl) * 64 + ss * 32 + klo);
            bf16x8 a10 = *(const bf16x8*)(sksrc + (rowb + 1 * 32 + 0 * 16 + xl) * 64 + ss * 32 + klo);
            bf16x8 a11 = *(const bf16x8*)(sksrc + (rowb + 1 * 32 + 1 * 16 + xl) * 64 + ss * 32 + klo);
            const short* bp = &bS[cur][0] + bOff;
            #pragma unroll
            for (int nb = 0; nb < 4; ++nb) {
                bf16x8 bf = *(const bf16x8*)(bp + nb * 128);
                acc[0][nb] = __builtin_amdgcn_mfma_f32_16x16x32_bf16(a00, bf, acc[0][nb], 0, 0, 0);
                acc[1][nb] = __builtin_amdgcn_mfma_f32_16x16x32_bf16(a01, bf, acc[1][nb], 0, 0, 0);
                acc[2][nb] = __builtin_amdgcn_mfma_f32_16x16x32_bf16(a10, bf, acc[2][nb], 0, 0, 0);
                acc[3][nb] = __builtin_amdgcn_mfma_f32_16x16x32_bf16(a11, bf, acc[3][nb], 0, 0, 0);
            }
            if (ks + 1 < NK) {
                ((uint4*)&bS[cur ^ 1][0])[tid] = qn0;
                ((uint4*)&bS[cur ^ 1][0])[tid + 256] = qn1;
            }
            __syncthreads();
            qn0 = r0; qn1 = r1;
            cur ^= 1; ++ks;
        }
    }

    // ---- epilogue ----
    float bv[4];
    #pragma unroll
    for (int nb = 0; nb < 4; ++nb) {
        int co = wn * 64 + nb * 16 + xl;
        if constexpr (SKIP) bv[nb] = bias[co] + bias2[co];
        else                bv[nb] = bias[co];
    }
    #pragma unroll
    for (int f = 0; f < 4; ++f) {
        const int fy = f >> 1, fx = f & 1;
        const int yrow = yo * 4 + wm * 2 + fy;
        const int xb2  = fx * 16 + q * 4;
        const int vox0 = vb + z * 1024 + yrow * 32 + xb2;
        float4 dm4 = *(const float4*)(dm + vox0);
        #pragma unroll
        for (int j = 0; j < 4; ++j) {
            const float dmx = (j == 0) ? dm4.x : (j == 1) ? dm4.y : (j == 2) ? dm4.z : dm4.w;
            const size_t obase = (size_t)(vox0 + j) * 128 + wn * 64 + xl;
            #pragma unroll
            for (int nb = 0; nb < 4; ++nb) {
                float o = (acc[f][nb][j] + bv[nb]) * dmx;
                if constexpr (SKIP) outf[obase + nb * 16] = o;
                else                outb[obase + nb * 16] = f2bf(o);
            }
        }
    }
}

// ---------------- Kernel 4: GN2 stats over h2a (bf16) ----------------
__global__ __launch_bounds__(256) void k4_stats2(const unsigned short* __restrict__ h2a,
                                                 const float* __restrict__ dm,
                                                 float* __restrict__ stats)
{
    __shared__ float ls1[32], ls2[32];
    __shared__ float lcnt;
    int tid = threadIdx.x;
    if (tid < 32) { ls1[tid] = 0.f; ls2[tid] = 0.f; }
    if (tid == 0) lcnt = 0.f;
    __syncthreads();

    int b  = blockIdx.x & 3;
    int bb = blockIdx.x >> 2;
    int g  = tid & 31;
    int vl = tid >> 5;

    const unsigned short* hb = h2a + ((size_t)b * V2) * C2;
    const float* dmb = dm + (size_t)b * V2;

    float s1 = 0.f, s2 = 0.f, mc = 0.f;
    for (int ch = bb; ch < V2 / 8; ch += 1024) {
        int v = ch * 8 + vl;
        float m = dmb[v];
        if (g == 0) mc += m;
        if (m != 0.f) {
            ushort4 hv = *(const ushort4*)(hb + (size_t)v * C2 + g * 4);
            float h0 = bf2f(hv.x), h1 = bf2f(hv.y), h2 = bf2f(hv.z), h3 = bf2f(hv.w);
            s1 += h0 + h1 + h2 + h3;
            s2 += h0 * h0 + h1 * h1 + h2 * h2 + h3 * h3;
        }
    }
    atomicAdd(&ls1[g], s1); atomicAdd(&ls2[g], s2);
    if (g == 0) atomicAdd(&lcnt, mc);
    __syncthreads();
    if (tid < 32) {
        atomicAdd(&stats[OFF_S1B + b * 32 + tid], ls1[tid]);
        atomicAdd(&stats[OFF_S2B + b * 32 + tid], ls2[tid]);
    }
    if (tid == 0) atomicAdd(&stats[OFF_CNT2 + b], lcnt);
}

// ---------------- Kernel 5: GN2 apply + SiLU -> h2b (bf16) ----------------
__global__ __launch_bounds__(256) void k5_gn2(const unsigned short* __restrict__ h2a,
                                              unsigned short* __restrict__ h2b,
                                              const float* __restrict__ stats,
                                              const float* __restrict__ dm,
                                              const float* __restrict__ gn2w,
                                              const float* __restrict__ gn2b)
{
    int idx = blockIdx.x * 256 + threadIdx.x;   // group-quad index
    int v = idx >> 5, g = idx & 31;
    int b = v >> 15;
    float ce   = fmaxf(stats[OFF_CNT2 + b] * 4.f, 1.f);
    float mean = stats[OFF_S1B + b * 32 + g] / ce;
    float var  = stats[OFF_S2B + b * 32 + g] / ce - mean * mean;
    float rinv = rsqrtf(var + 1e-5f);
    float dmv  = dm[v];
    ushort4 hv = *(const ushort4*)(h2a + (size_t)idx * 4);
    float4 gw = *(const float4*)(gn2w + g * 4);
    float4 gb = *(const float4*)(gn2b + g * 4);
    float a, t;
    ushort4 o;
    a = rinv * gw.x; t = (fmaf(bf2f(hv.x), a, gb.x - mean * a)) * dmv; o.x = f2bf(t / (1.f + expf(-t)));
    a = rinv * gw.y; t = (fmaf(bf2f(hv.y), a, gb.y - mean * a)) * dmv; o.y = f2bf(t / (1.f + expf(-t)));
    a = rinv * gw.z; t = (fmaf(bf2f(hv.z), a, gb.z - mean * a)) * dmv; o.z = f2bf(t / (1.f + expf(-t)));
    a = rinv * gw.w; t = (fmaf(bf2f(hv.w), a, gb.w - mean * a)) * dmv; o.w = f2bf(t / (1.f + expf(-t)));
    *(ushort4*)(h2b + (size_t)idx * 4) = o;
}

extern "C" void kernel_launch(void* const* d_in, const int* in_sizes, int n_in,
                              void* d_out, int out_size, void* d_ws, size_t ws_size,
                              hipStream_t stream)
{
    const float* x     = (const float*)d_in[0];
    const int*   mask  = (const int*)d_in[1];
    const float* gn1w  = (const float*)d_in[2];
    const float* gn1b  = (const float*)d_in[3];
    const float* w1    = (const float*)d_in[4];
    const float* b1    = (const float*)d_in[5];
    const float* gn2w  = (const float*)d_in[6];
    const float* gn2b  = (const float*)d_in[7];
    const float* w2    = (const float*)d_in[8];
    const float* b2    = (const float*)d_in[9];
    const float* wskip = (const float*)d_in[10];
    const float* bskip = (const float*)d_in[11];
    float* out = (float*)d_out;

    char* wsb = (char*)d_ws;
    float*          stats = (float*)wsb;                          // 520 f32
    float*          dm    = (float*)(wsb + 4096);                 // 131072 f32
    unsigned short* h1b   = (unsigned short*)(wsb + 528384);      // 131072*64 bf16
    unsigned short* xdb   = (unsigned short*)(wsb + 17305600);    // 131072*64 bf16
    unsigned short* h2a   = (unsigned short*)(wsb + 34082816);    // 131072*128 bf16
    unsigned short* h2b   = (unsigned short*)(wsb + 67637248);    // 131072*128 bf16
    unsigned short* w1t   = (unsigned short*)(wsb + 101191680);   // 54*4096 bf16
    unsigned short* w2t   = (unsigned short*)(wsb + 101634048);   // 110*4096 bf16

    hipMemsetAsync(stats, 0, 520 * sizeof(float), stream);

    hipLaunchKernelGGL(k0_wprep, dim3(2624), dim3(256), 0, stream, w1, w2, wskip, w1t, w2t);
    hipLaunchKernelGGL(k1_stats1, dim3(4096), dim3(256), 0, stream, x, mask, stats);
    hipLaunchKernelGGL(k2_down, dim3(32768), dim3(256), 0, stream,
                       x, mask, gn1w, gn1b, stats, h1b, xdb, dm);
    hipLaunchKernelGGL((conv3_mfma<64, false>), dim3(1024), dim3(256), 0, stream,
                       h1b, (const unsigned short*)nullptr, w1t, b1, (const float*)nullptr,
                       dm, (float*)nullptr, h2a);
    hipLaunchKernelGGL(k4_stats2, dim3(4096), dim3(256), 0, stream, h2a, dm, stats);
    hipLaunchKernelGGL(k5_gn2, dim3(16384), dim3(256), 0, stream, h2a, h2b, stats, dm, gn2w, gn2b);
    hipLaunchKernelGGL((conv3_mfma<128, true>), dim3(1024), dim3(256), 0, stream,
                       h2b, xdb, w2t, b2, bskip, dm, out, (unsigned short*)nullptr);
}